// Round 18
// baseline (144.353 us; speedup 1.0000x reference)
//
#include <hip/hip_runtime.h>
#include <hip/hip_bf16.h>

// Problem constants
#define B_ 16
#define N_ 512
#define H_ 8
#define D_ 128
#define HD_ 1024
#define SCALE_ 0.08838834764831845f  // 1/sqrt(128)

typedef __attribute__((ext_vector_type(8))) short bf16x8;     // 8 bf16 = 4 VGPR
typedef __attribute__((ext_vector_type(4))) float f32x4;      // MFMA 16x16 C/D
typedef __attribute__((ext_vector_type(4))) _Float16 f16x4;   // 16x16x16 A/B

__device__ __forceinline__ unsigned short f2bf(float f) {
    union { __hip_bfloat16 h; unsigned short u; } cv;
    cv.h = __float2bfloat16(f);
    return cv.u;
}
__device__ __forceinline__ unsigned short f2h(float f) {
    union { _Float16 h; unsigned short u; } cv;
    cv.h = (_Float16)f;
    return cv.u;
}

// Light barrier: LDS visibility only (no vmcnt drain; global prefetch
// loads stay in flight across it).
#define BAR_LIGHT() do {                                     \
    asm volatile("s_waitcnt lgkmcnt(0)" ::: "memory");       \
    __builtin_amdgcn_s_barrier();                            \
    asm volatile("" ::: "memory");                           \
} while (0)

// ---------------------------------------------------------------------------
// Kernel 0: prep. Tiles 0..383: Wq/Wk/Wv -> wTh [3][1024][128] bf16 (transposed).
// Tiles 384..511: Wo -> woT [128][1024] bf16 (transposed).
// Tiles 512..1023: x fp32 -> xh bf16 (R19 hoist; xh aliases yb, R20).
// ---------------------------------------------------------------------------
__global__ __launch_bounds__(256) void prep_kernel(
    const float* __restrict__ Wq, const float* __restrict__ Wk,
    const float* __restrict__ Wv, const float* __restrict__ Wo,
    const float* __restrict__ x,
    unsigned short* __restrict__ wTh, unsigned short* __restrict__ woT,
    unsigned short* __restrict__ xh)
{
    __shared__ float T[32][33];
    const int tile = blockIdx.x;
    const int t = threadIdx.x;
    if (tile < 384) {
        const int w = tile / 128;
        const int rem = tile % 128;
        const int kt = rem & 3;
        const int ct = rem >> 2;
        const float* W = (w == 0) ? Wq : (w == 1) ? Wk : Wv;
        const int k0 = kt * 32, c0 = ct * 32;
        #pragma unroll
        for (int u = 0; u < 4; u++) {
            int lin = t + 256 * u; int r = lin >> 5, c = lin & 31;
            T[r][c] = W[(size_t)(k0 + r) * 1024 + c0 + c];
        }
        BAR_LIGHT();
        unsigned short* oh = wTh + (size_t)w * 131072;
        #pragma unroll
        for (int u = 0; u < 4; u++) {
            int lin = t + 256 * u; int c = lin >> 5, r = lin & 31;
            oh[(size_t)(c0 + c) * 128 + k0 + r] = f2bf(T[r][c]);
        }
    } else if (tile < 512) {
        const int rem = tile - 384;
        const int nt = rem & 3;
        const int kt = rem >> 2;
        const int k0 = kt * 32, n0 = nt * 32;
        #pragma unroll
        for (int u = 0; u < 4; u++) {
            int lin = t + 256 * u; int r = lin >> 5, c = lin & 31;
            T[r][c] = Wo[(size_t)(k0 + r) * 128 + n0 + c];
        }
        BAR_LIGHT();
        #pragma unroll
        for (int u = 0; u < 4; u++) {
            int lin = t + 256 * u; int c = lin >> 5, r = lin & 31;
            woT[(size_t)(n0 + c) * 1024 + k0 + r] = f2bf(T[r][c]);
        }
    } else {
        // x -> bf16: 1,048,576 elements = 512 tiles x 2048; 8/thread
        const size_t base = (size_t)(tile - 512) * 2048 + (size_t)t * 8;
        float4 v0 = *(const float4*)&x[base];
        float4 v1 = *(const float4*)&x[base + 4];
        union { bf16x8 v; unsigned short s[8]; } H;
        H.s[0] = f2bf(v0.x); H.s[1] = f2bf(v0.y);
        H.s[2] = f2bf(v0.z); H.s[3] = f2bf(v0.w);
        H.s[4] = f2bf(v1.x); H.s[5] = f2bf(v1.y);
        H.s[6] = f2bf(v1.z); H.s[7] = f2bf(v1.w);
        *(bf16x8*)&xh[base] = H.v;
    }
}

// ---------------------------------------------------------------------------
// Kernel 1: QKV projection, 128 rows x 128 cols per block (grid 1536).
// R19: x as bf16 direct to registers. R22: swapped-operand q/k MFMA +
// vectorized ushort4 LDS transpose epilogue (load-bearing for write
// coalescing -- R27's direct-store epilogue regressed, write-side scatter).
// R23: light barriers. R26: XCD-affinity swizzle. R28: setprio.
// ---------------------------------------------------------------------------
__global__ __launch_bounds__(256, 3) void qkv_kernel(
    const unsigned short* __restrict__ xh, const float* __restrict__ mask,
    const unsigned short* __restrict__ wTh,
    const float* __restrict__ bq, const float* __restrict__ bk,
    const float* __restrict__ bv,
    unsigned short* __restrict__ q, unsigned short* __restrict__ k,
    unsigned short* __restrict__ vT)
{
    const int xid = blockIdx.x;
    const int hi = xid >> 3;
    const int bb = (xid & 7) + ((hi >= 96) ? 8 : 0);
    const int rem = hi % 96;
    const int cb = rem % 24;
    const int row0 = bb * 512 + (rem / 24) * 128;
    const int c0 = cb * 128;
    const int which = c0 >> 10, w0 = c0 & 1023;
    const float* bi = (which == 0) ? bq : (which == 1) ? bk : bv;

    __shared__ alignas(16) unsigned short Wh[128][136];  // 34.8 KB
    __shared__ float biS[128];
    __shared__ float mskS[128];

    const int t = threadIdx.x;
    if (t < 128) { biS[t] = bi[w0 + t]; mskS[t] = mask[row0 + t]; }

    const unsigned short* whp = wTh + (size_t)which * 131072 + (size_t)w0 * 128;
    #pragma unroll
    for (int u = 0; u < 8; u++) {
        int lin = t + 256 * u; int c = lin >> 4, k8 = (lin & 15) * 8;
        *(bf16x8*)&Wh[c][k8] = *(const bf16x8*)&whp[(size_t)c * 128 + k8];
    }

    const int wave = t >> 6, lane = t & 63, m16 = lane & 15, g4 = lane >> 4;
    const int rw = row0 + wave * 32;

    bf16x8 ah[2][4];
    #pragma unroll
    for (int mt = 0; mt < 2; mt++)
        #pragma unroll
        for (int kc = 0; kc < 4; kc++)
            ah[mt][kc] = *(const bf16x8*)&xh[(size_t)(rw + mt * 16 + m16) * 128 + kc * 32 + g4 * 8];
    BAR_LIGHT();

    const f32x4 zero = {0.f, 0.f, 0.f, 0.f};
    f32x4 acc[2][8];
    #pragma unroll
    for (int mt = 0; mt < 2; mt++)
        #pragma unroll
        for (int nt = 0; nt < 8; nt++) acc[mt][nt] = zero;

    __builtin_amdgcn_s_setprio(1);
    if (which == 2) {
        // v: D[x_row=g4*4+r][w_col=m16]
        #pragma unroll
        for (int nt = 0; nt < 8; nt++) {
            #pragma unroll
            for (int kc = 0; kc < 4; kc++) {
                bf16x8 bh = *(const bf16x8*)&Wh[nt * 16 + m16][kc * 32 + g4 * 8];
                #pragma unroll
                for (int mt = 0; mt < 2; mt++)
                    acc[mt][nt] = __builtin_amdgcn_mfma_f32_16x16x32_bf16(ah[mt][kc], bh, acc[mt][nt], 0, 0, 0);
            }
        }
    } else {
        // q/k swapped: D[w_col=g4*4+r][x_row=m16]
        #pragma unroll
        for (int nt = 0; nt < 8; nt++) {
            #pragma unroll
            for (int kc = 0; kc < 4; kc++) {
                bf16x8 bh = *(const bf16x8*)&Wh[nt * 16 + m16][kc * 32 + g4 * 8];
                #pragma unroll
                for (int mt = 0; mt < 2; mt++)
                    acc[mt][nt] = __builtin_amdgcn_mfma_f32_16x16x32_bf16(bh, ah[mt][kc], acc[mt][nt], 0, 0, 0);
            }
        }
    }
    __builtin_amdgcn_s_setprio(0);
    BAR_LIGHT();  // done reading Wh; reuse as transpose staging

    const int b = row0 >> 9, h = w0 >> 7;
    const int iseq0 = row0 & 511;
    unsigned short* Tr = &Wh[0][0];

    if (which == 2) {
        // lane: rows (wave*32+mt*16+g4*4 .. +3), col (nt*16+m16).
        // Tr staged v-transposed [col][row]: 4 rows contiguous -> ushort4.
        #pragma unroll
        for (int mt = 0; mt < 2; mt++)
            #pragma unroll
            for (int nt = 0; nt < 8; nt++) {
                int rowlb = wave * 32 + mt * 16 + g4 * 4;
                int col = nt * 16 + m16;
                float4 mk4 = *(const float4*)&mskS[rowlb];
                float bv4 = biS[col];
                ushort4 pk;
                pk.x = f2h((acc[mt][nt][0] + bv4) * mk4.x);
                pk.y = f2h((acc[mt][nt][1] + bv4) * mk4.y);
                pk.z = f2h((acc[mt][nt][2] + bv4) * mk4.z);
                pk.w = f2h((acc[mt][nt][3] + bv4) * mk4.w);
                *(ushort4*)&Tr[col * 136 + rowlb] = pk;
            }
        BAR_LIGHT();
        unsigned short* vbase = vT + (size_t)(b * 8 + h) * 128 * 512 + iseq0;
        #pragma unroll
        for (int u = 0; u < 8; u++) {
            int lin = t + 256 * u; int dl = lin >> 4, i8 = (lin & 15) * 8;
            *(bf16x8*)&vbase[(size_t)dl * 512 + i8] = *(const bf16x8*)&Tr[dl * 136 + i8];
        }
    } else {
        const float sc = (which == 0) ? SCALE_ : 1.0f;
        // swapped lane: row (wave*32+mt*16+m16), cols (nt*16+g4*4 .. +3).
        // Tr staged row-major: 4 cols contiguous -> ushort4.
        #pragma unroll
        for (int mt = 0; mt < 2; mt++)
            #pragma unroll
            for (int nt = 0; nt < 8; nt++) {
                int rowl = wave * 32 + mt * 16 + m16;
                int colb = nt * 16 + g4 * 4;
                float4 bi4 = *(const float4*)&biS[colb];
                float mk = mskS[rowl] * sc;
                ushort4 pk;
                pk.x = f2bf((acc[mt][nt][0] + bi4.x) * mk);
                pk.y = f2bf((acc[mt][nt][1] + bi4.y) * mk);
                pk.z = f2bf((acc[mt][nt][2] + bi4.z) * mk);
                pk.w = f2bf((acc[mt][nt][3] + bi4.w) * mk);
                *(ushort4*)&Tr[rowl * 136 + colb] = pk;
            }
        BAR_LIGHT();
        unsigned short* dst = ((which == 0) ? q : k) +
                              ((size_t)(b * 8 + h) * 512 + iseq0) * 128;
        #pragma unroll
        for (int u = 0; u < 8; u++) {
            int lin = t + 256 * u; int rl = lin >> 4, c8 = (lin & 15) * 8;
            *(bf16x8*)&dst[(size_t)rl * 128 + c8] = *(const bf16x8*)&Tr[rl * 136 + c8];
        }
    }
}

// ---------------------------------------------------------------------------
// Kernel 2: flash attention, S^T trick. R22/R23 structure + R25 setprio
// (41.3 us measured). K AND V in LDS (per-wave reads at the byte-once
// floor; more rows/wave = R24 spill cliff; global feed = R18 2x loss).
// R29: column mask via GLOBAL broadcast loads instead of cmS LDS --
// moves 8 reads/chunk/wave off the ~95%-saturated LDS pipe onto the
// ~15%-utilized VMEM pipe (mask = 32KB, L2-resident; 16 lanes share
// each address -> 1 transaction). cm recomputed as fmaf(m,1e9,-1e9)
// (exactly 0 or -1e9, bit-identical exp args). cmS deleted (-2KB LDS).
// ---------------------------------------------------------------------------
__global__ __launch_bounds__(256, 2) void attn_kernel(
    const unsigned short* __restrict__ q, const unsigned short* __restrict__ k,
    const unsigned short* __restrict__ vT, const float* __restrict__ dist,
    const float* __restrict__ mask, unsigned short* __restrict__ y)
{
    const int xid = blockIdx.x;                       // 512 blocks
    // XCD = xid % 8 = b & 7: one batch per XCD at a time (L2-sized set).
    const int b = (xid & 7) | ((xid >> 8) << 3);
    const int itile = (xid >> 3) & 3;                 // 4 itiles x 128 rows
    const int h = (xid >> 5) & 7;
    const int bh = b * 8 + h;
    const int i0 = itile * 128;

    const unsigned short* qb = q + (size_t)bh * 512 * 128;
    const unsigned short* kb = k + (size_t)bh * 512 * 128;
    const unsigned short* vb = vT + (size_t)bh * 128 * 512;  // f16 (d, j)

    __shared__ alignas(16) unsigned short Ks[2][64][136];   // 34816 B
    __shared__ alignas(16) unsigned short Vs[2][128][76];   // 38912 B

    const int t = threadIdx.x;
    const int wave = t >> 6, lane = t & 63;
    const int m16 = lane & 15, g4 = lane >> 4;
    const int iw = i0 + wave * 32;                    // wave owns rows iw..iw+31

    // Q fragments for both i-tiles: MFMA B-operand (n=i=m16, k=d)
    bf16x8 aq0[4], aq1[4];
    #pragma unroll
    for (int c = 0; c < 4; c++) {
        aq0[c] = *(const bf16x8*)(qb + (size_t)(iw + m16) * 128 + c * 32 + g4 * 8);
        aq1[c] = *(const bf16x8*)(qb + (size_t)(iw + 16 + m16) * 128 + c * 32 + g4 * 8);
    }

    const int krow = t >> 2, kcol = (t & 3) * 32;
    const int vrow = t >> 1, vcol = (t & 1) * 32;

    const float* dbase = dist + ((size_t)b * 512 + iw) * 512;
    const float* mbase = mask + (size_t)b * 512;

    // prologue: chunk 0 -> regs -> buf0
    bf16x8 kp[4], vp[4];
    #pragma unroll
    for (int u = 0; u < 4; u++) {
        kp[u] = *(const bf16x8*)(kb + (size_t)krow * 128 + kcol + u * 8);
        vp[u] = *(const bf16x8*)(vb + (size_t)vrow * 512 + vcol + u * 8);
    }
    #pragma unroll
    for (int u = 0; u < 4; u++) {
        *(bf16x8*)&Ks[0][krow][kcol + u * 8] = kp[u];
        union { bf16x8 v8; ushort4 h4[2]; } cv; cv.v8 = vp[u];
        *(ushort4*)&Vs[0][vrow][vcol + u * 8] = cv.h4[0];
        *(ushort4*)&Vs[0][vrow][vcol + u * 8 + 4] = cv.h4[1];
    }
    BAR_LIGHT();

    const f32x4 zero = {0.f, 0.f, 0.f, 0.f};
    float rl0 = 0.f, rl1 = 0.f;   // per-lane partial row sums, tiles 0/1
    f32x4 Ot0[8] = {zero, zero, zero, zero, zero, zero, zero, zero};
    f32x4 Ot1[8] = {zero, zero, zero, zero, zero, zero, zero, zero};

    for (int c = 0; c < 8; c++) {
        const int j0 = c * 64;
        const int bsel = c & 1;

        // prefetch next chunk K/V into regs (depth-1)
        if (c < 7) {
            const int j0n = j0 + 64;
            #pragma unroll
            for (int u = 0; u < 4; u++) {
                kp[u] = *(const bf16x8*)(kb + (size_t)(j0n + krow) * 128 + kcol + u * 8);
                vp[u] = *(const bf16x8*)(vb + (size_t)vrow * 512 + j0n + vcol + u * 8);
            }
        }

        // dist + column-mask loads for this chunk (global, L2-hot);
        // consumed post-MFMA so QK covers their latency
        f32x4 dv0[4], dv1[4], mv[4];
        #pragma unroll
        for (int jt = 0; jt < 4; jt++) {
            dv0[jt] = *(const f32x4*)&dbase[(size_t)m16 * 512 + j0 + jt * 16 + g4 * 4];
            dv1[jt] = *(const f32x4*)&dbase[(size_t)(16 + m16) * 512 + j0 + jt * 16 + g4 * 4];
            mv[jt]  = *(const f32x4*)&mbase[j0 + jt * 16 + g4 * 4];
        }

        // QK: S^T = K*Q^T, each kf read feeds BOTH i-tiles
        f32x4 s0[4], s1[4];
        __builtin_amdgcn_s_setprio(1);
        #pragma unroll
        for (int jt = 0; jt < 4; jt++) {
            f32x4 a0 = zero, a1 = zero;
            #pragma unroll
            for (int cc = 0; cc < 4; cc++) {
                bf16x8 kf = *(const bf16x8*)&Ks[bsel][jt * 16 + m16][cc * 32 + g4 * 8];
                a0 = __builtin_amdgcn_mfma_f32_16x16x32_bf16(kf, aq0[cc], a0, 0, 0, 0);
                a1 = __builtin_amdgcn_mfma_f32_16x16x32_bf16(kf, aq1[cc], a1, 0, 0, 0);
            }
            s0[jt] = a0; s1[jt] = a1;
        }
        __builtin_amdgcn_s_setprio(0);

        // P = exp(s + dist + colmask); cm = fmaf(m,1e9,-1e9) = 0 or -1e9
        f16x4 pa0[4], pa1[4];
        float ps0 = 0.f, ps1 = 0.f;
        #pragma unroll
        for (int jt = 0; jt < 4; jt++) {
            #pragma unroll
            for (int r = 0; r < 4; r++) {
                float cmr = fmaf(mv[jt][r], 1e9f, -1e9f);
                float p0 = __expf(s0[jt][r] + dv0[jt][r] + cmr);
                float p1 = __expf(s1[jt][r] + dv1[jt][r] + cmr);
                ps0 += p0; ps1 += p1;
                pa0[jt][r] = (_Float16)p0;
                pa1[jt][r] = (_Float16)p1;
            }
        }
        rl0 += ps0; rl1 += ps1;

        // stage next chunk into the other LDS buffer
        if (c < 7) {
            const int bo = bsel ^ 1;
            #pragma unroll
            for (int u = 0; u < 4; u++) {
                *(bf16x8*)&Ks[bo][krow][kcol + u * 8] = kp[u];
                union { bf16x8 v8; ushort4 h4[2]; } cv; cv.v8 = vp[u];
                *(ushort4*)&Vs[bo][vrow][vcol + u * 8] = cv.h4[0];
                *(ushort4*)&Vs[bo][vrow][vcol + u * 8 + 4] = cv.h4[1];
            }
        }

        // PV: each vf read feeds BOTH i-tiles
        __builtin_amdgcn_s_setprio(1);
        #pragma unroll
        for (int jt = 0; jt < 4; jt++)
            #pragma unroll
            for (int dt = 0; dt < 8; dt++) {
                f16x4 vf = *(const f16x4*)&Vs[bsel][dt * 16 + m16][jt * 16 + g4 * 4];
                Ot0[dt] = __builtin_amdgcn_mfma_f32_16x16x16f16(pa0[jt], vf, Ot0[dt], 0, 0, 0);
                Ot1[dt] = __builtin_amdgcn_mfma_f32_16x16x16f16(pa1[jt], vf, Ot1[dt], 0, 0, 0);
            }
        __builtin_amdgcn_s_setprio(0);

        if (c < 7) BAR_LIGHT();
    }
    BAR_LIGHT();   // all waves done reading Ks/Vs before epilogue reuse

    // epilogue: reduce row sums (deferred), normalize, stage in Ks[0]/Ks[1]
    rl0 += __shfl_xor(rl0, 16); rl0 += __shfl_xor(rl0, 32);
    rl1 += __shfl_xor(rl1, 16); rl1 += __shfl_xor(rl1, 32);
    float rs0 = (rl0 > 0.f) ? 1.0f / rl0 : 0.f;
    float rs1 = (rl1 > 0.f) ? 1.0f / rl1 : 0.f;
    float rs04[4], rs14[4];
    #pragma unroll
    for (int r = 0; r < 4; r++) {
        rs04[r] = __shfl(rs0, g4 * 4 + r);
        rs14[r] = __shfl(rs1, g4 * 4 + r);
    }
    // wave w -> buffer w>>1, local rows (w&1)*32 .. +31 (wave-local)
    unsigned short (*Sb)[136] = (wave >> 1) ? Ks[1] : Ks[0];
    const int rb = (wave & 1) * 32;
    #pragma unroll
    for (int dt = 0; dt < 8; dt++)
        #pragma unroll
        for (int r = 0; r < 4; r++) {
            Sb[rb + g4 * 4 + r][dt * 16 + m16]      = f2bf(Ot0[dt][r] * rs04[r]);
            Sb[rb + 16 + g4 * 4 + r][dt * 16 + m16] = f2bf(Ot1[dt][r] * rs14[r]);
        }
    #pragma unroll
    for (int u = 0; u < 8; u++) {
        int lin = lane + 64 * u;       // 0..511
        int row = lin >> 4;            // 0..31
        int seg = lin & 15;
        *(bf16x8*)&y[((size_t)(b * 512) + iw + row) * 1024 + h * 128 + seg * 8] =
            *(const bf16x8*)&Sb[rb + row][seg * 8];
    }
}

// ---------------------------------------------------------------------------
// Kernel 3: output projection (R20 structure: 16-row blocks, grid 512,
// 2 blocks/CU, depth-1 prefetch; R23 light barriers; R26 XCD affinity;
// R28 setprio).
// ---------------------------------------------------------------------------
__global__ __launch_bounds__(256, 2) void oproj_kernel(
    const unsigned short* __restrict__ Y, const unsigned short* __restrict__ woT,
    const float* __restrict__ bo, const float* __restrict__ mask,
    float* __restrict__ out)
{
    const int xid = blockIdx.x;
    const int hi = xid >> 3;
    const int bb = (xid & 7) + ((hi >= 32) ? 8 : 0);
    const int row0 = bb * 512 + (hi % 32) * 16;
    __shared__ alignas(16) unsigned short Ys[16][136];
    __shared__ alignas(16) unsigned short Ws[128][136];
    __shared__ float boS[128];
    __shared__ float mskS[16];

    const int t = threadIdx.x;
    if (t < 128) boS[t] = bo[t];
    if (t < 16) mskS[t] = mask[row0 + t];

    const int wave = t >> 6, lane = t & 63;
    const int m16 = lane & 15, g4 = lane >> 4;
    const int n0 = wave * 32;               // each wave: 32 output cols

    const int yr = t >> 4, yk = (t & 15) * 8;   // 16 rows x 128 cols staging
    const int wn = t >> 4, wk = (t & 15) * 8;

    const f32x4 zero = {0.f, 0.f, 0.f, 0.f};
    f32x4 acc[2] = {zero, zero};

    bf16x8 yp, wp[8];
    yp = *(const bf16x8*)&Y[(size_t)(row0 + yr) * 1024 + yk];
    #pragma unroll
    for (int u = 0; u < 8; u++)
        wp[u] = *(const bf16x8*)&woT[(size_t)(wn + u * 16) * 1024 + wk];

    for (int c = 0; c < 8; c++) {
        BAR_LIGHT();   // all waves done reading Ys/Ws from previous chunk
        *(bf16x8*)&Ys[yr][yk] = yp;
        #pragma unroll
        for (int u = 0; u < 8; u++) *(bf16x8*)&Ws[wn + u * 16][wk] = wp[u];
        BAR_LIGHT();   // staging visible
        if (c < 7) {
            const int kc0 = (c + 1) * 128;
            yp = *(const bf16x8*)&Y[(size_t)(row0 + yr) * 1024 + kc0 + yk];
            #pragma unroll
            for (int u = 0; u < 8; u++)
                wp[u] = *(const bf16x8*)&woT[(size_t)(wn + u * 16) * 1024 + kc0 + wk];
        }
        __builtin_amdgcn_s_setprio(1);
        #pragma unroll
        for (int kc = 0; kc < 4; kc++) {
            bf16x8 a = *(const bf16x8*)&Ys[m16][kc * 32 + g4 * 8];
            #pragma unroll
            for (int nt = 0; nt < 2; nt++) {
                bf16x8 bb2 = *(const bf16x8*)&Ws[n0 + nt * 16 + m16][kc * 32 + g4 * 8];
                acc[nt] = __builtin_amdgcn_mfma_f32_16x16x32_bf16(a, bb2, acc[nt], 0, 0, 0);
            }
        }
        __builtin_amdgcn_s_setprio(0);
    }
    BAR_LIGHT();   // done reading Ws; reuse as fp32 epilogue staging

    float* Ot = (float*)&Ws[0][0];  // stride 132, 16x132 floats fits in Ws
    #pragma unroll
    for (int nt = 0; nt < 2; nt++)
        #pragma unroll
        for (int r = 0; r < 4; r++) {
            int rowl = g4 * 4 + r;
            int col = n0 + nt * 16 + m16;
            Ot[rowl * 132 + col] = (acc[nt][r] + boS[col]) * mskS[rowl];
        }
    BAR_LIGHT();
    #pragma unroll
    for (int u = 0; u < 2; u++) {
        int lin = t + 256 * u; int r = lin >> 5, c4 = lin & 31;
        *(float4*)&out[(size_t)(row0 + r) * 128 + c4 * 4] =
            *(const float4*)&Ot[r * 132 + c4 * 4];
    }
}

extern "C" void kernel_launch(void* const* d_in, const int* in_sizes, int n_in,
                              void* d_out, int out_size, void* d_ws, size_t ws_size,
                              hipStream_t stream) {
    const float* x    = (const float*)d_in[0];
    const float* dist = (const float*)d_in[1];
    const float* mask = (const float*)d_in[2];
    const float* Wq   = (const float*)d_in[3];
    const float* bq   = (const float*)d_in[4];
    const float* Wk   = (const float*)d_in[5];
    const float* bk   = (const float*)d_in[6];
    const float* Wv   = (const float*)d_in[7];
    const float* bv   = (const float*)d_in[8];
    const float* Wo   = (const float*)d_in[9];
    const float* bo   = (const float*)d_in[10];
    float* out = (float*)d_out;

    const size_t perE = (size_t)B_ * H_ * N_ * D_;     // 8,388,608 elements
    unsigned short* qb  = (unsigned short*)d_ws;       // bf16 (B,H,N,D)
    unsigned short* kb  = qb + perE;                   // bf16 (B,H,N,D)
    unsigned short* vb  = kb + perE;                   // f16  (B,H,D,N)
    unsigned short* yb  = vb + perE;                   // bf16 (B,N,H*D)
    unsigned short* wTh = yb + perE;                   // [3][1024][128]
    unsigned short* woT = wTh + 3 * 131072;            // [128][1024]
    // xh ALIASES yb: xh written by prep, read by qkv; yb first written by
    // attn (after qkv). Lifetimes disjoint; footprint = R17 layout exactly.
    unsigned short* xh  = yb;                          // bf16 x (B,N,D) 1M elems

    prep_kernel<<<1024, 256, 0, stream>>>(Wq, Wk, Wv, Wo, x, wTh, woT, xh);
    qkv_kernel<<<1536, 256, 0, stream>>>(xh, mask, wTh, bq, bk, bv, qb, kb, vb);
    attn_kernel<<<512, 256, 0, stream>>>(qb, kb, vb, dist, mask, yb);
    oproj_kernel<<<512, 256, 0, stream>>>(yb, woT, bo, mask, out);
}

// Round 19
// 143.376 us; speedup vs baseline: 1.0068x; 1.0068x over previous
//
#include <hip/hip_runtime.h>
#include <hip/hip_bf16.h>

// ============================================================================
// FINAL (R30 = R25 exact, best measured: 143.2 us total, attn 41.3 us).
// Session: 160 -> 143.2. Key wins: R17 32-rows/wave (LDS amplification
// halved, -21% attn), R19/R20 x->bf16 hoist (~5 us), R25 setprio (+5% attn).
// Plateau: attn is dependency-latency-floored at this tiling (all pipes
// <30%, insensitive to occupancy/prefetch-depth/traffic/VALU cuts); deeper
// restructures hit measured spill (R24) or scatter (R18/R27) cliffs.
// ============================================================================
#define B_ 16
#define N_ 512
#define H_ 8
#define D_ 128
#define HD_ 1024
#define SCALE_ 0.08838834764831845f  // 1/sqrt(128)

typedef __attribute__((ext_vector_type(8))) short bf16x8;     // 8 bf16 = 4 VGPR
typedef __attribute__((ext_vector_type(4))) float f32x4;      // MFMA 16x16 C/D
typedef __attribute__((ext_vector_type(4))) _Float16 f16x4;   // 16x16x16 A/B

__device__ __forceinline__ unsigned short f2bf(float f) {
    union { __hip_bfloat16 h; unsigned short u; } cv;
    cv.h = __float2bfloat16(f);
    return cv.u;
}
__device__ __forceinline__ unsigned short f2h(float f) {
    union { _Float16 h; unsigned short u; } cv;
    cv.h = (_Float16)f;
    return cv.u;
}

// Light barrier: LDS visibility only (no vmcnt drain; global prefetch
// loads stay in flight across it).
#define BAR_LIGHT() do {                                     \
    asm volatile("s_waitcnt lgkmcnt(0)" ::: "memory");       \
    __builtin_amdgcn_s_barrier();                            \
    asm volatile("" ::: "memory");                           \
} while (0)

// ---------------------------------------------------------------------------
// Kernel 0: prep. Tiles 0..383: Wq/Wk/Wv -> wTh [3][1024][128] bf16 (transposed).
// Tiles 384..511: Wo -> woT [128][1024] bf16 (transposed).
// Tiles 512..1023: x fp32 -> xh bf16 (R19 hoist; xh aliases yb, R20).
// ---------------------------------------------------------------------------
__global__ __launch_bounds__(256) void prep_kernel(
    const float* __restrict__ Wq, const float* __restrict__ Wk,
    const float* __restrict__ Wv, const float* __restrict__ Wo,
    const float* __restrict__ x,
    unsigned short* __restrict__ wTh, unsigned short* __restrict__ woT,
    unsigned short* __restrict__ xh)
{
    __shared__ float T[32][33];
    const int tile = blockIdx.x;
    const int t = threadIdx.x;
    if (tile < 384) {
        const int w = tile / 128;
        const int rem = tile % 128;
        const int kt = rem & 3;
        const int ct = rem >> 2;
        const float* W = (w == 0) ? Wq : (w == 1) ? Wk : Wv;
        const int k0 = kt * 32, c0 = ct * 32;
        #pragma unroll
        for (int u = 0; u < 4; u++) {
            int lin = t + 256 * u; int r = lin >> 5, c = lin & 31;
            T[r][c] = W[(size_t)(k0 + r) * 1024 + c0 + c];
        }
        BAR_LIGHT();
        unsigned short* oh = wTh + (size_t)w * 131072;
        #pragma unroll
        for (int u = 0; u < 4; u++) {
            int lin = t + 256 * u; int c = lin >> 5, r = lin & 31;
            oh[(size_t)(c0 + c) * 128 + k0 + r] = f2bf(T[r][c]);
        }
    } else if (tile < 512) {
        const int rem = tile - 384;
        const int nt = rem & 3;
        const int kt = rem >> 2;
        const int k0 = kt * 32, n0 = nt * 32;
        #pragma unroll
        for (int u = 0; u < 4; u++) {
            int lin = t + 256 * u; int r = lin >> 5, c = lin & 31;
            T[r][c] = Wo[(size_t)(k0 + r) * 128 + n0 + c];
        }
        BAR_LIGHT();
        #pragma unroll
        for (int u = 0; u < 4; u++) {
            int lin = t + 256 * u; int c = lin >> 5, r = lin & 31;
            woT[(size_t)(n0 + c) * 1024 + k0 + r] = f2bf(T[r][c]);
        }
    } else {
        // x -> bf16: 1,048,576 elements = 512 tiles x 2048; 8/thread
        const size_t base = (size_t)(tile - 512) * 2048 + (size_t)t * 8;
        float4 v0 = *(const float4*)&x[base];
        float4 v1 = *(const float4*)&x[base + 4];
        union { bf16x8 v; unsigned short s[8]; } H;
        H.s[0] = f2bf(v0.x); H.s[1] = f2bf(v0.y);
        H.s[2] = f2bf(v0.z); H.s[3] = f2bf(v0.w);
        H.s[4] = f2bf(v1.x); H.s[5] = f2bf(v1.y);
        H.s[6] = f2bf(v1.z); H.s[7] = f2bf(v1.w);
        *(bf16x8*)&xh[base] = H.v;
    }
}

// ---------------------------------------------------------------------------
// Kernel 1: QKV projection, 128 rows x 128 cols per block (grid 1536).
// R19: x consumed as bf16 (xh) direct to registers. R22: swapped-operand
// q/k MFMA -> vectorized ushort4 LDS transpose epilogue (load-bearing for
// write coalescing, R27 proved). R23: light barriers.
// ---------------------------------------------------------------------------
__global__ __launch_bounds__(256, 3) void qkv_kernel(
    const unsigned short* __restrict__ xh, const float* __restrict__ mask,
    const unsigned short* __restrict__ wTh,
    const float* __restrict__ bq, const float* __restrict__ bk,
    const float* __restrict__ bv,
    unsigned short* __restrict__ q, unsigned short* __restrict__ k,
    unsigned short* __restrict__ vT)
{
    const int cb = blockIdx.x % 24;
    const int by = blockIdx.x / 24;
    const int row0 = by * 128, c0 = cb * 128;
    const int which = c0 >> 10, w0 = c0 & 1023;
    const float* bi = (which == 0) ? bq : (which == 1) ? bk : bv;

    __shared__ alignas(16) unsigned short Wh[128][136];  // 34.8 KB
    __shared__ float biS[128];
    __shared__ float mskS[128];

    const int t = threadIdx.x;
    if (t < 128) { biS[t] = bi[w0 + t]; mskS[t] = mask[row0 + t]; }

    const unsigned short* whp = wTh + (size_t)which * 131072 + (size_t)w0 * 128;
    #pragma unroll
    for (int u = 0; u < 8; u++) {
        int lin = t + 256 * u; int c = lin >> 4, k8 = (lin & 15) * 8;
        *(bf16x8*)&Wh[c][k8] = *(const bf16x8*)&whp[(size_t)c * 128 + k8];
    }

    const int wave = t >> 6, lane = t & 63, m16 = lane & 15, g4 = lane >> 4;
    const int rw = row0 + wave * 32;

    bf16x8 ah[2][4];
    #pragma unroll
    for (int mt = 0; mt < 2; mt++)
        #pragma unroll
        for (int kc = 0; kc < 4; kc++)
            ah[mt][kc] = *(const bf16x8*)&xh[(size_t)(rw + mt * 16 + m16) * 128 + kc * 32 + g4 * 8];
    BAR_LIGHT();

    const f32x4 zero = {0.f, 0.f, 0.f, 0.f};
    f32x4 acc[2][8];
    #pragma unroll
    for (int mt = 0; mt < 2; mt++)
        #pragma unroll
        for (int nt = 0; nt < 8; nt++) acc[mt][nt] = zero;

    if (which == 2) {
        // v: D[x_row=g4*4+r][w_col=m16]
        #pragma unroll
        for (int nt = 0; nt < 8; nt++) {
            #pragma unroll
            for (int kc = 0; kc < 4; kc++) {
                bf16x8 bh = *(const bf16x8*)&Wh[nt * 16 + m16][kc * 32 + g4 * 8];
                #pragma unroll
                for (int mt = 0; mt < 2; mt++)
                    acc[mt][nt] = __builtin_amdgcn_mfma_f32_16x16x32_bf16(ah[mt][kc], bh, acc[mt][nt], 0, 0, 0);
            }
        }
    } else {
        // q/k swapped: D[w_col=g4*4+r][x_row=m16]
        #pragma unroll
        for (int nt = 0; nt < 8; nt++) {
            #pragma unroll
            for (int kc = 0; kc < 4; kc++) {
                bf16x8 bh = *(const bf16x8*)&Wh[nt * 16 + m16][kc * 32 + g4 * 8];
                #pragma unroll
                for (int mt = 0; mt < 2; mt++)
                    acc[mt][nt] = __builtin_amdgcn_mfma_f32_16x16x32_bf16(bh, ah[mt][kc], acc[mt][nt], 0, 0, 0);
            }
        }
    }
    BAR_LIGHT();  // done reading Wh; reuse as transpose staging

    const int b = row0 >> 9, h = w0 >> 7;
    const int iseq0 = row0 & 511;
    unsigned short* Tr = &Wh[0][0];

    if (which == 2) {
        // lane: rows (wave*32+mt*16+g4*4 .. +3), col (nt*16+m16).
        // Tr staged v-transposed [col][row]: 4 rows contiguous -> ushort4.
        #pragma unroll
        for (int mt = 0; mt < 2; mt++)
            #pragma unroll
            for (int nt = 0; nt < 8; nt++) {
                int rowlb = wave * 32 + mt * 16 + g4 * 4;
                int col = nt * 16 + m16;
                float4 mk4 = *(const float4*)&mskS[rowlb];
                float bv4 = biS[col];
                ushort4 pk;
                pk.x = f2h((acc[mt][nt][0] + bv4) * mk4.x);
                pk.y = f2h((acc[mt][nt][1] + bv4) * mk4.y);
                pk.z = f2h((acc[mt][nt][2] + bv4) * mk4.z);
                pk.w = f2h((acc[mt][nt][3] + bv4) * mk4.w);
                *(ushort4*)&Tr[col * 136 + rowlb] = pk;
            }
        BAR_LIGHT();
        unsigned short* vbase = vT + (size_t)(b * 8 + h) * 128 * 512 + iseq0;
        #pragma unroll
        for (int u = 0; u < 8; u++) {
            int lin = t + 256 * u; int dl = lin >> 4, i8 = (lin & 15) * 8;
            *(bf16x8*)&vbase[(size_t)dl * 512 + i8] = *(const bf16x8*)&Tr[dl * 136 + i8];
        }
    } else {
        const float sc = (which == 0) ? SCALE_ : 1.0f;
        // swapped lane: row (wave*32+mt*16+m16), cols (nt*16+g4*4 .. +3).
        // Tr staged row-major: 4 cols contiguous -> ushort4.
        #pragma unroll
        for (int mt = 0; mt < 2; mt++)
            #pragma unroll
            for (int nt = 0; nt < 8; nt++) {
                int rowl = wave * 32 + mt * 16 + m16;
                int colb = nt * 16 + g4 * 4;
                float4 bi4 = *(const float4*)&biS[colb];
                float mk = mskS[rowl] * sc;
                ushort4 pk;
                pk.x = f2bf((acc[mt][nt][0] + bi4.x) * mk);
                pk.y = f2bf((acc[mt][nt][1] + bi4.y) * mk);
                pk.z = f2bf((acc[mt][nt][2] + bi4.z) * mk);
                pk.w = f2bf((acc[mt][nt][3] + bi4.w) * mk);
                *(ushort4*)&Tr[rowl * 136 + colb] = pk;
            }
        BAR_LIGHT();
        unsigned short* dst = ((which == 0) ? q : k) +
                              ((size_t)(b * 8 + h) * 512 + iseq0) * 128;
        #pragma unroll
        for (int u = 0; u < 8; u++) {
            int lin = t + 256 * u; int rl = lin >> 4, c8 = (lin & 15) * 8;
            *(bf16x8*)&dst[(size_t)rl * 128 + c8] = *(const bf16x8*)&Tr[rl * 136 + c8];
        }
    }
}

// ---------------------------------------------------------------------------
// Kernel 2: flash attention, S^T trick (41.3 us measured). K AND V in LDS
// (per-wave reads at the byte-once floor; global feeds 2-4x worse R11/R18).
// 32 q-rows/wave (R17), no-max softmax (R16), XCD=b (R15), light barriers
// (R14), depth-1 K/V prefetch, setprio around MFMA clusters (R25).
// ---------------------------------------------------------------------------
__global__ __launch_bounds__(256, 2) void attn_kernel(
    const unsigned short* __restrict__ q, const unsigned short* __restrict__ k,
    const unsigned short* __restrict__ vT, const float* __restrict__ dist,
    const float* __restrict__ mask, unsigned short* __restrict__ y)
{
    const int xid = blockIdx.x;                       // 512 blocks
    // XCD = xid % 8 = b & 7: one batch per XCD at a time (L2-sized set).
    const int b = (xid & 7) | ((xid >> 8) << 3);
    const int itile = (xid >> 3) & 3;                 // 4 itiles x 128 rows
    const int h = (xid >> 5) & 7;
    const int bh = b * 8 + h;
    const int i0 = itile * 128;

    const unsigned short* qb = q + (size_t)bh * 512 * 128;
    const unsigned short* kb = k + (size_t)bh * 512 * 128;
    const unsigned short* vb = vT + (size_t)bh * 128 * 512;  // f16 (d, j)

    __shared__ alignas(16) unsigned short Ks[2][64][136];   // 34816 B
    __shared__ alignas(16) unsigned short Vs[2][128][76];   // 38912 B
    __shared__ alignas(16) float cmS[512];                  // 2048 B

    const int t = threadIdx.x;
    const int wave = t >> 6, lane = t & 63;
    const int m16 = lane & 15, g4 = lane >> 4;
    const int iw = i0 + wave * 32;                    // wave owns rows iw..iw+31

    cmS[t] = (mask[b * 512 + t] == 0.0f) ? -1e9f : 0.0f;
    cmS[256 + t] = (mask[b * 512 + 256 + t] == 0.0f) ? -1e9f : 0.0f;

    // Q fragments for both i-tiles: MFMA B-operand (n=i=m16, k=d)
    bf16x8 aq0[4], aq1[4];
    #pragma unroll
    for (int c = 0; c < 4; c++) {
        aq0[c] = *(const bf16x8*)(qb + (size_t)(iw + m16) * 128 + c * 32 + g4 * 8);
        aq1[c] = *(const bf16x8*)(qb + (size_t)(iw + 16 + m16) * 128 + c * 32 + g4 * 8);
    }

    const int krow = t >> 2, kcol = (t & 3) * 32;
    const int vrow = t >> 1, vcol = (t & 1) * 32;

    const float* dbase = dist + ((size_t)b * 512 + iw) * 512;

    // prologue: chunk 0 -> regs -> buf0
    bf16x8 kp[4], vp[4];
    #pragma unroll
    for (int u = 0; u < 4; u++) {
        kp[u] = *(const bf16x8*)(kb + (size_t)krow * 128 + kcol + u * 8);
        vp[u] = *(const bf16x8*)(vb + (size_t)vrow * 512 + vcol + u * 8);
    }
    #pragma unroll
    for (int u = 0; u < 4; u++) {
        *(bf16x8*)&Ks[0][krow][kcol + u * 8] = kp[u];
        union { bf16x8 v8; ushort4 h4[2]; } cv; cv.v8 = vp[u];
        *(ushort4*)&Vs[0][vrow][vcol + u * 8] = cv.h4[0];
        *(ushort4*)&Vs[0][vrow][vcol + u * 8 + 4] = cv.h4[1];
    }
    BAR_LIGHT();

    const f32x4 zero = {0.f, 0.f, 0.f, 0.f};
    float rl0 = 0.f, rl1 = 0.f;   // per-lane partial row sums, tiles 0/1
    f32x4 Ot0[8] = {zero, zero, zero, zero, zero, zero, zero, zero};
    f32x4 Ot1[8] = {zero, zero, zero, zero, zero, zero, zero, zero};

    for (int c = 0; c < 8; c++) {
        const int j0 = c * 64;
        const int bsel = c & 1;

        // prefetch next chunk K/V into regs (depth-1)
        if (c < 7) {
            const int j0n = j0 + 64;
            #pragma unroll
            for (int u = 0; u < 4; u++) {
                kp[u] = *(const bf16x8*)(kb + (size_t)(j0n + krow) * 128 + kcol + u * 8);
                vp[u] = *(const bf16x8*)(vb + (size_t)vrow * 512 + j0n + vcol + u * 8);
            }
        }

        // dist loads for this chunk, both tiles (L2-hot); consumed post-MFMA
        f32x4 dv0[4], dv1[4];
        #pragma unroll
        for (int jt = 0; jt < 4; jt++) {
            dv0[jt] = *(const f32x4*)&dbase[(size_t)m16 * 512 + j0 + jt * 16 + g4 * 4];
            dv1[jt] = *(const f32x4*)&dbase[(size_t)(16 + m16) * 512 + j0 + jt * 16 + g4 * 4];
        }

        // QK: S^T = K*Q^T, each kf read feeds BOTH i-tiles
        f32x4 s0[4], s1[4];
        __builtin_amdgcn_s_setprio(1);
        #pragma unroll
        for (int jt = 0; jt < 4; jt++) {
            f32x4 a0 = zero, a1 = zero;
            #pragma unroll
            for (int cc = 0; cc < 4; cc++) {
                bf16x8 kf = *(const bf16x8*)&Ks[bsel][jt * 16 + m16][cc * 32 + g4 * 8];
                a0 = __builtin_amdgcn_mfma_f32_16x16x32_bf16(kf, aq0[cc], a0, 0, 0, 0);
                a1 = __builtin_amdgcn_mfma_f32_16x16x32_bf16(kf, aq1[cc], a1, 0, 0, 0);
            }
            s0[jt] = a0; s1[jt] = a1;
        }
        __builtin_amdgcn_s_setprio(0);

        // P = exp(s + dist + colmask); per-lane partial row sums only
        f16x4 pa0[4], pa1[4];
        float ps0 = 0.f, ps1 = 0.f;
        #pragma unroll
        for (int jt = 0; jt < 4; jt++) {
            f32x4 cm4 = *(const f32x4*)&cmS[j0 + jt * 16 + g4 * 4];
            #pragma unroll
            for (int r = 0; r < 4; r++) {
                float p0 = __expf(s0[jt][r] + dv0[jt][r] + cm4[r]);
                float p1 = __expf(s1[jt][r] + dv1[jt][r] + cm4[r]);
                ps0 += p0; ps1 += p1;
                pa0[jt][r] = (_Float16)p0;
                pa1[jt][r] = (_Float16)p1;
            }
        }
        rl0 += ps0; rl1 += ps1;

        // stage next chunk into the other LDS buffer
        if (c < 7) {
            const int bo = bsel ^ 1;
            #pragma unroll
            for (int u = 0; u < 4; u++) {
                *(bf16x8*)&Ks[bo][krow][kcol + u * 8] = kp[u];
                union { bf16x8 v8; ushort4 h4[2]; } cv; cv.v8 = vp[u];
                *(ushort4*)&Vs[bo][vrow][vcol + u * 8] = cv.h4[0];
                *(ushort4*)&Vs[bo][vrow][vcol + u * 8 + 4] = cv.h4[1];
            }
        }

        // PV: each vf read feeds BOTH i-tiles
        __builtin_amdgcn_s_setprio(1);
        #pragma unroll
        for (int jt = 0; jt < 4; jt++)
            #pragma unroll
            for (int dt = 0; dt < 8; dt++) {
                f16x4 vf = *(const f16x4*)&Vs[bsel][dt * 16 + m16][jt * 16 + g4 * 4];
                Ot0[dt] = __builtin_amdgcn_mfma_f32_16x16x16f16(pa0[jt], vf, Ot0[dt], 0, 0, 0);
                Ot1[dt] = __builtin_amdgcn_mfma_f32_16x16x16f16(pa1[jt], vf, Ot1[dt], 0, 0, 0);
            }
        __builtin_amdgcn_s_setprio(0);

        if (c < 7) BAR_LIGHT();
    }
    BAR_LIGHT();   // all waves done reading Ks/Vs before epilogue reuse

    // epilogue: reduce row sums (deferred), normalize, stage in Ks[0]/Ks[1]
    rl0 += __shfl_xor(rl0, 16); rl0 += __shfl_xor(rl0, 32);
    rl1 += __shfl_xor(rl1, 16); rl1 += __shfl_xor(rl1, 32);
    float rs0 = (rl0 > 0.f) ? 1.0f / rl0 : 0.f;
    float rs1 = (rl1 > 0.f) ? 1.0f / rl1 : 0.f;
    float rs04[4], rs14[4];
    #pragma unroll
    for (int r = 0; r < 4; r++) {
        rs04[r] = __shfl(rs0, g4 * 4 + r);
        rs14[r] = __shfl(rs1, g4 * 4 + r);
    }
    // wave w -> buffer w>>1, local rows (w&1)*32 .. +31 (wave-local)
    unsigned short (*Sb)[136] = (wave >> 1) ? Ks[1] : Ks[0];
    const int rb = (wave & 1) * 32;
    #pragma unroll
    for (int dt = 0; dt < 8; dt++)
        #pragma unroll
        for (int r = 0; r < 4; r++) {
            Sb[rb + g4 * 4 + r][dt * 16 + m16]      = f2bf(Ot0[dt][r] * rs04[r]);
            Sb[rb + 16 + g4 * 4 + r][dt * 16 + m16] = f2bf(Ot1[dt][r] * rs14[r]);
        }
    #pragma unroll
    for (int u = 0; u < 8; u++) {
        int lin = lane + 64 * u;       // 0..511
        int row = lin >> 4;            // 0..31
        int seg = lin & 15;
        *(bf16x8*)&y[((size_t)(b * 512) + iw + row) * 1024 + h * 128 + seg * 8] =
            *(const bf16x8*)&Sb[rb + row][seg * 8];
    }
}

// ---------------------------------------------------------------------------
// Kernel 3: output projection (R20 structure: 16-row blocks, grid 512,
// 2 blocks/CU, depth-1 register prefetch; R23 light barriers).
// ---------------------------------------------------------------------------
__global__ __launch_bounds__(256, 2) void oproj_kernel(
    const unsigned short* __restrict__ Y, const unsigned short* __restrict__ woT,
    const float* __restrict__ bo, const float* __restrict__ mask,
    float* __restrict__ out)
{
    const int row0 = blockIdx.x * 16;
    __shared__ alignas(16) unsigned short Ys[16][136];
    __shared__ alignas(16) unsigned short Ws[128][136];
    __shared__ float boS[128];
    __shared__ float mskS[16];

    const int t = threadIdx.x;
    if (t < 128) boS[t] = bo[t];
    if (t < 16) mskS[t] = mask[row0 + t];

    const int wave = t >> 6, lane = t & 63;
    const int m16 = lane & 15, g4 = lane >> 4;
    const int n0 = wave * 32;               // each wave: 32 output cols

    const int yr = t >> 4, yk = (t & 15) * 8;   // 16 rows x 128 cols staging
    const int wn = t >> 4, wk = (t & 15) * 8;

    const f32x4 zero = {0.f, 0.f, 0.f, 0.f};
    f32x4 acc[2] = {zero, zero};

    bf16x8 yp, wp[8];
    yp = *(const bf16x8*)&Y[(size_t)(row0 + yr) * 1024 + yk];
    #pragma unroll
    for (int u = 0; u < 8; u++)
        wp[u] = *(const bf16x8*)&woT[(size_t)(wn + u * 16) * 1024 + wk];

    for (int c = 0; c < 8; c++) {
        BAR_LIGHT();   // all waves done reading Ys/Ws from previous chunk
        *(bf16x8*)&Ys[yr][yk] = yp;
        #pragma unroll
        for (int u = 0; u < 8; u++) *(bf16x8*)&Ws[wn + u * 16][wk] = wp[u];
        BAR_LIGHT();   // staging visible
        if (c < 7) {
            const int kc0 = (c + 1) * 128;
            yp = *(const bf16x8*)&Y[(size_t)(row0 + yr) * 1024 + kc0 + yk];
            #pragma unroll
            for (int u = 0; u < 8; u++)
                wp[u] = *(const bf16x8*)&woT[(size_t)(wn + u * 16) * 1024 + kc0 + wk];
        }
        #pragma unroll
        for (int kc = 0; kc < 4; kc++) {
            bf16x8 a = *(const bf16x8*)&Ys[m16][kc * 32 + g4 * 8];
            #pragma unroll
            for (int nt = 0; nt < 2; nt++) {
                bf16x8 bb = *(const bf16x8*)&Ws[n0 + nt * 16 + m16][kc * 32 + g4 * 8];
                acc[nt] = __builtin_amdgcn_mfma_f32_16x16x32_bf16(a, bb, acc[nt], 0, 0, 0);
            }
        }
    }
    BAR_LIGHT();   // done reading Ws; reuse as fp32 epilogue staging

    float* Ot = (float*)&Ws[0][0];  // stride 132, 16x132 floats fits in Ws
    #pragma unroll
    for (int nt = 0; nt < 2; nt++)
        #pragma unroll
        for (int r = 0; r < 4; r++) {
            int rowl = g4 * 4 + r;
            int col = n0 + nt * 16 + m16;
            Ot[rowl * 132 + col] = (acc[nt][r] + boS[col]) * mskS[rowl];
        }
    BAR_LIGHT();
    #pragma unroll
    for (int u = 0; u < 2; u++) {
        int lin = t + 256 * u; int r = lin >> 5, c4 = lin & 31;
        *(float4*)&out[(size_t)(row0 + r) * 128 + c4 * 4] =
            *(const float4*)&Ot[r * 132 + c4 * 4];
    }
}

extern "C" void kernel_launch(void* const* d_in, const int* in_sizes, int n_in,
                              void* d_out, int out_size, void* d_ws, size_t ws_size,
                              hipStream_t stream) {
    const float* x    = (const float*)d_in[0];
    const float* dist = (const float*)d_in[1];
    const float* mask = (const float*)d_in[2];
    const float* Wq   = (const float*)d_in[3];
    const float* bq   = (const float*)d_in[4];
    const float* Wk   = (const float*)d_in[5];
    const float* bk   = (const float*)d_in[6];
    const float* Wv   = (const float*)d_in[7];
    const float* bv   = (const float*)d_in[8];
    const float* Wo   = (const float*)d_in[9];
    const float* bo   = (const float*)d_in[10];
    float* out = (float*)d_out;

    const size_t perE = (size_t)B_ * H_ * N_ * D_;     // 8,388,608 elements
    unsigned short* qb  = (unsigned short*)d_ws;       // bf16 (B,H,N,D)
    unsigned short* kb  = qb + perE;                   // bf16 (B,H,N,D)
    unsigned short* vb  = kb + perE;                   // f16  (B,H,D,N)
    unsigned short* yb  = vb + perE;                   // bf16 (B,N,H*D)
    unsigned short* wTh = yb + perE;                   // [3][1024][128]
    unsigned short* woT = wTh + 3 * 131072;            // [128][1024]
    // xh ALIASES yb: xh written by prep, read by qkv; yb first written by
    // attn (after qkv). Lifetimes disjoint; footprint = R17 layout exactly.
    unsigned short* xh  = yb;                          // bf16 x (B,N,D) 1M elems

    prep_kernel<<<1024, 256, 0, stream>>>(Wq, Wk, Wv, Wo, x, wTh, woT, xh);
    qkv_kernel<<<1536, 256, 0, stream>>>(xh, mask, wTh, bq, bk, bv, qb, kb, vb);
    attn_kernel<<<512, 256, 0, stream>>>(qb, kb, vb, dist, mask, yb);
    oproj_kernel<<<512, 256, 0, stream>>>(yb, woT, bo, mask, out);
}

// Round 20
// 142.617 us; speedup vs baseline: 1.0122x; 1.0053x over previous
//
#include <hip/hip_runtime.h>
#include <hip/hip_bf16.h>

// ============================================================================
// FINAL (R25/R30 configuration, measured 143.2-143.5 us across three runs;
// attn 41.3-42.3 us, VGPR 116, FETCH 32.86 MB, conflicts 1,638,400).
// Session: 160.2 -> 143.4 us. Validated wins:
//   R17: 32 q-rows/wave (LDS read amplification halved; -21% attn)
//   R19/R20: x fp32->bf16 hoisted to prep (~5 us; xh aliases yb)
//   R25: s_setprio around attn MFMA clusters (+5% attn)
// Validated negative results (measured cliffs bounding this design):
//   R11/R18/R27: global feeds / direct-store epilogues -> access scatter 2-4x
//   R24: deeper unroll/prefetch -> VGPR spill (WRITE 16->51MB scratch)
//   R12: occupancy bump regresses; R13/R14/R23: pipeline/barrier neutral
//   R15: -64% bytes, duration invariant; R16: -30% VALU, invariant
// attn is dependency-latency-floored at this tiling: all pipes <30%.
// ============================================================================
#define B_ 16
#define N_ 512
#define H_ 8
#define D_ 128
#define HD_ 1024
#define SCALE_ 0.08838834764831845f  // 1/sqrt(128)

typedef __attribute__((ext_vector_type(8))) short bf16x8;     // 8 bf16 = 4 VGPR
typedef __attribute__((ext_vector_type(4))) float f32x4;      // MFMA 16x16 C/D
typedef __attribute__((ext_vector_type(4))) _Float16 f16x4;   // 16x16x16 A/B

__device__ __forceinline__ unsigned short f2bf(float f) {
    union { __hip_bfloat16 h; unsigned short u; } cv;
    cv.h = __float2bfloat16(f);
    return cv.u;
}
__device__ __forceinline__ unsigned short f2h(float f) {
    union { _Float16 h; unsigned short u; } cv;
    cv.h = (_Float16)f;
    return cv.u;
}

// Light barrier: LDS visibility only (no vmcnt drain; global prefetch
// loads stay in flight across it).
#define BAR_LIGHT() do {                                     \
    asm volatile("s_waitcnt lgkmcnt(0)" ::: "memory");       \
    __builtin_amdgcn_s_barrier();                            \
    asm volatile("" ::: "memory");                           \
} while (0)

// ---------------------------------------------------------------------------
// Kernel 0: prep. Tiles 0..383: Wq/Wk/Wv -> wTh [3][1024][128] bf16 (transposed).
// Tiles 384..511: Wo -> woT [128][1024] bf16 (transposed).
// Tiles 512..1023: x fp32 -> xh bf16 (R19 hoist; xh aliases yb, R20).
// ---------------------------------------------------------------------------
__global__ __launch_bounds__(256) void prep_kernel(
    const float* __restrict__ Wq, const float* __restrict__ Wk,
    const float* __restrict__ Wv, const float* __restrict__ Wo,
    const float* __restrict__ x,
    unsigned short* __restrict__ wTh, unsigned short* __restrict__ woT,
    unsigned short* __restrict__ xh)
{
    __shared__ float T[32][33];
    const int tile = blockIdx.x;
    const int t = threadIdx.x;
    if (tile < 384) {
        const int w = tile / 128;
        const int rem = tile % 128;
        const int kt = rem & 3;
        const int ct = rem >> 2;
        const float* W = (w == 0) ? Wq : (w == 1) ? Wk : Wv;
        const int k0 = kt * 32, c0 = ct * 32;
        #pragma unroll
        for (int u = 0; u < 4; u++) {
            int lin = t + 256 * u; int r = lin >> 5, c = lin & 31;
            T[r][c] = W[(size_t)(k0 + r) * 1024 + c0 + c];
        }
        BAR_LIGHT();
        unsigned short* oh = wTh + (size_t)w * 131072;
        #pragma unroll
        for (int u = 0; u < 4; u++) {
            int lin = t + 256 * u; int c = lin >> 5, r = lin & 31;
            oh[(size_t)(c0 + c) * 128 + k0 + r] = f2bf(T[r][c]);
        }
    } else if (tile < 512) {
        const int rem = tile - 384;
        const int nt = rem & 3;
        const int kt = rem >> 2;
        const int k0 = kt * 32, n0 = nt * 32;
        #pragma unroll
        for (int u = 0; u < 4; u++) {
            int lin = t + 256 * u; int r = lin >> 5, c = lin & 31;
            T[r][c] = Wo[(size_t)(k0 + r) * 128 + n0 + c];
        }
        BAR_LIGHT();
        #pragma unroll
        for (int u = 0; u < 4; u++) {
            int lin = t + 256 * u; int c = lin >> 5, r = lin & 31;
            woT[(size_t)(n0 + c) * 1024 + k0 + r] = f2bf(T[r][c]);
        }
    } else {
        // x -> bf16: 1,048,576 elements = 512 tiles x 2048; 8/thread
        const size_t base = (size_t)(tile - 512) * 2048 + (size_t)t * 8;
        float4 v0 = *(const float4*)&x[base];
        float4 v1 = *(const float4*)&x[base + 4];
        union { bf16x8 v; unsigned short s[8]; } H;
        H.s[0] = f2bf(v0.x); H.s[1] = f2bf(v0.y);
        H.s[2] = f2bf(v0.z); H.s[3] = f2bf(v0.w);
        H.s[4] = f2bf(v1.x); H.s[5] = f2bf(v1.y);
        H.s[6] = f2bf(v1.z); H.s[7] = f2bf(v1.w);
        *(bf16x8*)&xh[base] = H.v;
    }
}

// ---------------------------------------------------------------------------
// Kernel 1: QKV projection, 128 rows x 128 cols per block (grid 1536).
// R19: x consumed as bf16 (xh) direct to registers. R22: swapped-operand
// q/k MFMA -> vectorized ushort4 LDS transpose epilogue (load-bearing for
// write coalescing, R27 proved). R23: light barriers.
// ---------------------------------------------------------------------------
__global__ __launch_bounds__(256, 3) void qkv_kernel(
    const unsigned short* __restrict__ xh, const float* __restrict__ mask,
    const unsigned short* __restrict__ wTh,
    const float* __restrict__ bq, const float* __restrict__ bk,
    const float* __restrict__ bv,
    unsigned short* __restrict__ q, unsigned short* __restrict__ k,
    unsigned short* __restrict__ vT)
{
    const int cb = blockIdx.x % 24;
    const int by = blockIdx.x / 24;
    const int row0 = by * 128, c0 = cb * 128;
    const int which = c0 >> 10, w0 = c0 & 1023;
    const float* bi = (which == 0) ? bq : (which == 1) ? bk : bv;

    __shared__ alignas(16) unsigned short Wh[128][136];  // 34.8 KB
    __shared__ float biS[128];
    __shared__ float mskS[128];

    const int t = threadIdx.x;
    if (t < 128) { biS[t] = bi[w0 + t]; mskS[t] = mask[row0 + t]; }

    const unsigned short* whp = wTh + (size_t)which * 131072 + (size_t)w0 * 128;
    #pragma unroll
    for (int u = 0; u < 8; u++) {
        int lin = t + 256 * u; int c = lin >> 4, k8 = (lin & 15) * 8;
        *(bf16x8*)&Wh[c][k8] = *(const bf16x8*)&whp[(size_t)c * 128 + k8];
    }

    const int wave = t >> 6, lane = t & 63, m16 = lane & 15, g4 = lane >> 4;
    const int rw = row0 + wave * 32;

    bf16x8 ah[2][4];
    #pragma unroll
    for (int mt = 0; mt < 2; mt++)
        #pragma unroll
        for (int kc = 0; kc < 4; kc++)
            ah[mt][kc] = *(const bf16x8*)&xh[(size_t)(rw + mt * 16 + m16) * 128 + kc * 32 + g4 * 8];
    BAR_LIGHT();

    const f32x4 zero = {0.f, 0.f, 0.f, 0.f};
    f32x4 acc[2][8];
    #pragma unroll
    for (int mt = 0; mt < 2; mt++)
        #pragma unroll
        for (int nt = 0; nt < 8; nt++) acc[mt][nt] = zero;

    if (which == 2) {
        // v: D[x_row=g4*4+r][w_col=m16]
        #pragma unroll
        for (int nt = 0; nt < 8; nt++) {
            #pragma unroll
            for (int kc = 0; kc < 4; kc++) {
                bf16x8 bh = *(const bf16x8*)&Wh[nt * 16 + m16][kc * 32 + g4 * 8];
                #pragma unroll
                for (int mt = 0; mt < 2; mt++)
                    acc[mt][nt] = __builtin_amdgcn_mfma_f32_16x16x32_bf16(ah[mt][kc], bh, acc[mt][nt], 0, 0, 0);
            }
        }
    } else {
        // q/k swapped: D[w_col=g4*4+r][x_row=m16]
        #pragma unroll
        for (int nt = 0; nt < 8; nt++) {
            #pragma unroll
            for (int kc = 0; kc < 4; kc++) {
                bf16x8 bh = *(const bf16x8*)&Wh[nt * 16 + m16][kc * 32 + g4 * 8];
                #pragma unroll
                for (int mt = 0; mt < 2; mt++)
                    acc[mt][nt] = __builtin_amdgcn_mfma_f32_16x16x32_bf16(bh, ah[mt][kc], acc[mt][nt], 0, 0, 0);
            }
        }
    }
    BAR_LIGHT();  // done reading Wh; reuse as transpose staging

    const int b = row0 >> 9, h = w0 >> 7;
    const int iseq0 = row0 & 511;
    unsigned short* Tr = &Wh[0][0];

    if (which == 2) {
        // lane: rows (wave*32+mt*16+g4*4 .. +3), col (nt*16+m16).
        // Tr staged v-transposed [col][row]: 4 rows contiguous -> ushort4.
        #pragma unroll
        for (int mt = 0; mt < 2; mt++)
            #pragma unroll
            for (int nt = 0; nt < 8; nt++) {
                int rowlb = wave * 32 + mt * 16 + g4 * 4;
                int col = nt * 16 + m16;
                float4 mk4 = *(const float4*)&mskS[rowlb];
                float bv4 = biS[col];
                ushort4 pk;
                pk.x = f2h((acc[mt][nt][0] + bv4) * mk4.x);
                pk.y = f2h((acc[mt][nt][1] + bv4) * mk4.y);
                pk.z = f2h((acc[mt][nt][2] + bv4) * mk4.z);
                pk.w = f2h((acc[mt][nt][3] + bv4) * mk4.w);
                *(ushort4*)&Tr[col * 136 + rowlb] = pk;
            }
        BAR_LIGHT();
        unsigned short* vbase = vT + (size_t)(b * 8 + h) * 128 * 512 + iseq0;
        #pragma unroll
        for (int u = 0; u < 8; u++) {
            int lin = t + 256 * u; int dl = lin >> 4, i8 = (lin & 15) * 8;
            *(bf16x8*)&vbase[(size_t)dl * 512 + i8] = *(const bf16x8*)&Tr[dl * 136 + i8];
        }
    } else {
        const float sc = (which == 0) ? SCALE_ : 1.0f;
        // swapped lane: row (wave*32+mt*16+m16), cols (nt*16+g4*4 .. +3).
        // Tr staged row-major: 4 cols contiguous -> ushort4.
        #pragma unroll
        for (int mt = 0; mt < 2; mt++)
            #pragma unroll
            for (int nt = 0; nt < 8; nt++) {
                int rowl = wave * 32 + mt * 16 + m16;
                int colb = nt * 16 + g4 * 4;
                float4 bi4 = *(const float4*)&biS[colb];
                float mk = mskS[rowl] * sc;
                ushort4 pk;
                pk.x = f2bf((acc[mt][nt][0] + bi4.x) * mk);
                pk.y = f2bf((acc[mt][nt][1] + bi4.y) * mk);
                pk.z = f2bf((acc[mt][nt][2] + bi4.z) * mk);
                pk.w = f2bf((acc[mt][nt][3] + bi4.w) * mk);
                *(ushort4*)&Tr[rowl * 136 + colb] = pk;
            }
        BAR_LIGHT();
        unsigned short* dst = ((which == 0) ? q : k) +
                              ((size_t)(b * 8 + h) * 512 + iseq0) * 128;
        #pragma unroll
        for (int u = 0; u < 8; u++) {
            int lin = t + 256 * u; int rl = lin >> 4, c8 = (lin & 15) * 8;
            *(bf16x8*)&dst[(size_t)rl * 128 + c8] = *(const bf16x8*)&Tr[rl * 136 + c8];
        }
    }
}

// ---------------------------------------------------------------------------
// Kernel 2: flash attention, S^T trick (41.3-42.3 us measured). K AND V in
// LDS (per-wave reads at the byte-once floor; global feeds 2-4x worse
// R11/R18). 32 q-rows/wave (R17), no-max softmax (R16), XCD=b (R15),
// light barriers (R14), depth-1 K/V prefetch, setprio (R25).
// ---------------------------------------------------------------------------
__global__ __launch_bounds__(256, 2) void attn_kernel(
    const unsigned short* __restrict__ q, const unsigned short* __restrict__ k,
    const unsigned short* __restrict__ vT, const float* __restrict__ dist,
    const float* __restrict__ mask, unsigned short* __restrict__ y)
{
    const int xid = blockIdx.x;                       // 512 blocks
    // XCD = xid % 8 = b & 7: one batch per XCD at a time (L2-sized set).
    const int b = (xid & 7) | ((xid >> 8) << 3);
    const int itile = (xid >> 3) & 3;                 // 4 itiles x 128 rows
    const int h = (xid >> 5) & 7;
    const int bh = b * 8 + h;
    const int i0 = itile * 128;

    const unsigned short* qb = q + (size_t)bh * 512 * 128;
    const unsigned short* kb = k + (size_t)bh * 512 * 128;
    const unsigned short* vb = vT + (size_t)bh * 128 * 512;  // f16 (d, j)

    __shared__ alignas(16) unsigned short Ks[2][64][136];   // 34816 B
    __shared__ alignas(16) unsigned short Vs[2][128][76];   // 38912 B
    __shared__ alignas(16) float cmS[512];                  // 2048 B

    const int t = threadIdx.x;
    const int wave = t >> 6, lane = t & 63;
    const int m16 = lane & 15, g4 = lane >> 4;
    const int iw = i0 + wave * 32;                    // wave owns rows iw..iw+31

    cmS[t] = (mask[b * 512 + t] == 0.0f) ? -1e9f : 0.0f;
    cmS[256 + t] = (mask[b * 512 + 256 + t] == 0.0f) ? -1e9f : 0.0f;

    // Q fragments for both i-tiles: MFMA B-operand (n=i=m16, k=d)
    bf16x8 aq0[4], aq1[4];
    #pragma unroll
    for (int c = 0; c < 4; c++) {
        aq0[c] = *(const bf16x8*)(qb + (size_t)(iw + m16) * 128 + c * 32 + g4 * 8);
        aq1[c] = *(const bf16x8*)(qb + (size_t)(iw + 16 + m16) * 128 + c * 32 + g4 * 8);
    }

    const int krow = t >> 2, kcol = (t & 3) * 32;
    const int vrow = t >> 1, vcol = (t & 1) * 32;

    const float* dbase = dist + ((size_t)b * 512 + iw) * 512;

    // prologue: chunk 0 -> regs -> buf0
    bf16x8 kp[4], vp[4];
    #pragma unroll
    for (int u = 0; u < 4; u++) {
        kp[u] = *(const bf16x8*)(kb + (size_t)krow * 128 + kcol + u * 8);
        vp[u] = *(const bf16x8*)(vb + (size_t)vrow * 512 + vcol + u * 8);
    }
    #pragma unroll
    for (int u = 0; u < 4; u++) {
        *(bf16x8*)&Ks[0][krow][kcol + u * 8] = kp[u];
        union { bf16x8 v8; ushort4 h4[2]; } cv; cv.v8 = vp[u];
        *(ushort4*)&Vs[0][vrow][vcol + u * 8] = cv.h4[0];
        *(ushort4*)&Vs[0][vrow][vcol + u * 8 + 4] = cv.h4[1];
    }
    BAR_LIGHT();

    const f32x4 zero = {0.f, 0.f, 0.f, 0.f};
    float rl0 = 0.f, rl1 = 0.f;   // per-lane partial row sums, tiles 0/1
    f32x4 Ot0[8] = {zero, zero, zero, zero, zero, zero, zero, zero};
    f32x4 Ot1[8] = {zero, zero, zero, zero, zero, zero, zero, zero};

    for (int c = 0; c < 8; c++) {
        const int j0 = c * 64;
        const int bsel = c & 1;

        // prefetch next chunk K/V into regs (depth-1)
        if (c < 7) {
            const int j0n = j0 + 64;
            #pragma unroll
            for (int u = 0; u < 4; u++) {
                kp[u] = *(const bf16x8*)(kb + (size_t)(j0n + krow) * 128 + kcol + u * 8);
                vp[u] = *(const bf16x8*)(vb + (size_t)vrow * 512 + j0n + vcol + u * 8);
            }
        }

        // dist loads for this chunk, both tiles (L2-hot); consumed post-MFMA
        f32x4 dv0[4], dv1[4];
        #pragma unroll
        for (int jt = 0; jt < 4; jt++) {
            dv0[jt] = *(const f32x4*)&dbase[(size_t)m16 * 512 + j0 + jt * 16 + g4 * 4];
            dv1[jt] = *(const f32x4*)&dbase[(size_t)(16 + m16) * 512 + j0 + jt * 16 + g4 * 4];
        }

        // QK: S^T = K*Q^T, each kf read feeds BOTH i-tiles
        f32x4 s0[4], s1[4];
        __builtin_amdgcn_s_setprio(1);
        #pragma unroll
        for (int jt = 0; jt < 4; jt++) {
            f32x4 a0 = zero, a1 = zero;
            #pragma unroll
            for (int cc = 0; cc < 4; cc++) {
                bf16x8 kf = *(const bf16x8*)&Ks[bsel][jt * 16 + m16][cc * 32 + g4 * 8];
                a0 = __builtin_amdgcn_mfma_f32_16x16x32_bf16(kf, aq0[cc], a0, 0, 0, 0);
                a1 = __builtin_amdgcn_mfma_f32_16x16x32_bf16(kf, aq1[cc], a1, 0, 0, 0);
            }
            s0[jt] = a0; s1[jt] = a1;
        }
        __builtin_amdgcn_s_setprio(0);

        // P = exp(s + dist + colmask); per-lane partial row sums only
        f16x4 pa0[4], pa1[4];
        float ps0 = 0.f, ps1 = 0.f;
        #pragma unroll
        for (int jt = 0; jt < 4; jt++) {
            f32x4 cm4 = *(const f32x4*)&cmS[j0 + jt * 16 + g4 * 4];
            #pragma unroll
            for (int r = 0; r < 4; r++) {
                float p0 = __expf(s0[jt][r] + dv0[jt][r] + cm4[r]);
                float p1 = __expf(s1[jt][r] + dv1[jt][r] + cm4[r]);
                ps0 += p0; ps1 += p1;
                pa0[jt][r] = (_Float16)p0;
                pa1[jt][r] = (_Float16)p1;
            }
        }
        rl0 += ps0; rl1 += ps1;

        // stage next chunk into the other LDS buffer
        if (c < 7) {
            const int bo = bsel ^ 1;
            #pragma unroll
            for (int u = 0; u < 4; u++) {
                *(bf16x8*)&Ks[bo][krow][kcol + u * 8] = kp[u];
                union { bf16x8 v8; ushort4 h4[2]; } cv; cv.v8 = vp[u];
                *(ushort4*)&Vs[bo][vrow][vcol + u * 8] = cv.h4[0];
                *(ushort4*)&Vs[bo][vrow][vcol + u * 8 + 4] = cv.h4[1];
            }
        }

        // PV: each vf read feeds BOTH i-tiles
        __builtin_amdgcn_s_setprio(1);
        #pragma unroll
        for (int jt = 0; jt < 4; jt++)
            #pragma unroll
            for (int dt = 0; dt < 8; dt++) {
                f16x4 vf = *(const f16x4*)&Vs[bsel][dt * 16 + m16][jt * 16 + g4 * 4];
                Ot0[dt] = __builtin_amdgcn_mfma_f32_16x16x16f16(pa0[jt], vf, Ot0[dt], 0, 0, 0);
                Ot1[dt] = __builtin_amdgcn_mfma_f32_16x16x16f16(pa1[jt], vf, Ot1[dt], 0, 0, 0);
            }
        __builtin_amdgcn_s_setprio(0);

        if (c < 7) BAR_LIGHT();
    }
    BAR_LIGHT();   // all waves done reading Ks/Vs before epilogue reuse

    // epilogue: reduce row sums (deferred), normalize, stage in Ks[0]/Ks[1]
    rl0 += __shfl_xor(rl0, 16); rl0 += __shfl_xor(rl0, 32);
    rl1 += __shfl_xor(rl1, 16); rl1 += __shfl_xor(rl1, 32);
    float rs0 = (rl0 > 0.f) ? 1.0f / rl0 : 0.f;
    float rs1 = (rl1 > 0.f) ? 1.0f / rl1 : 0.f;
    float rs04[4], rs14[4];
    #pragma unroll
    for (int r = 0; r < 4; r++) {
        rs04[r] = __shfl(rs0, g4 * 4 + r);
        rs14[r] = __shfl(rs1, g4 * 4 + r);
    }
    // wave w -> buffer w>>1, local rows (w&1)*32 .. +31 (wave-local)
    unsigned short (*Sb)[136] = (wave >> 1) ? Ks[1] : Ks[0];
    const int rb = (wave & 1) * 32;
    #pragma unroll
    for (int dt = 0; dt < 8; dt++)
        #pragma unroll
        for (int r = 0; r < 4; r++) {
            Sb[rb + g4 * 4 + r][dt * 16 + m16]      = f2bf(Ot0[dt][r] * rs04[r]);
            Sb[rb + 16 + g4 * 4 + r][dt * 16 + m16] = f2bf(Ot1[dt][r] * rs14[r]);
        }
    #pragma unroll
    for (int u = 0; u < 8; u++) {
        int lin = lane + 64 * u;       // 0..511
        int row = lin >> 4;            // 0..31
        int seg = lin & 15;
        *(bf16x8*)&y[((size_t)(b * 512) + iw + row) * 1024 + h * 128 + seg * 8] =
            *(const bf16x8*)&Sb[rb + row][seg * 8];
    }
}

// ---------------------------------------------------------------------------
// Kernel 3: output projection (R20 structure: 16-row blocks, grid 512,
// 2 blocks/CU, depth-1 register prefetch; R23 light barriers).
// ---------------------------------------------------------------------------
__global__ __launch_bounds__(256, 2) void oproj_kernel(
    const unsigned short* __restrict__ Y, const unsigned short* __restrict__ woT,
    const float* __restrict__ bo, const float* __restrict__ mask,
    float* __restrict__ out)
{
    const int row0 = blockIdx.x * 16;
    __shared__ alignas(16) unsigned short Ys[16][136];
    __shared__ alignas(16) unsigned short Ws[128][136];
    __shared__ float boS[128];
    __shared__ float mskS[16];

    const int t = threadIdx.x;
    if (t < 128) boS[t] = bo[t];
    if (t < 16) mskS[t] = mask[row0 + t];

    const int wave = t >> 6, lane = t & 63;
    const int m16 = lane & 15, g4 = lane >> 4;
    const int n0 = wave * 32;               // each wave: 32 output cols

    const int yr = t >> 4, yk = (t & 15) * 8;   // 16 rows x 128 cols staging
    const int wn = t >> 4, wk = (t & 15) * 8;

    const f32x4 zero = {0.f, 0.f, 0.f, 0.f};
    f32x4 acc[2] = {zero, zero};

    bf16x8 yp, wp[8];
    yp = *(const bf16x8*)&Y[(size_t)(row0 + yr) * 1024 + yk];
    #pragma unroll
    for (int u = 0; u < 8; u++)
        wp[u] = *(const bf16x8*)&woT[(size_t)(wn + u * 16) * 1024 + wk];

    for (int c = 0; c < 8; c++) {
        BAR_LIGHT();   // all waves done reading Ys/Ws from previous chunk
        *(bf16x8*)&Ys[yr][yk] = yp;
        #pragma unroll
        for (int u = 0; u < 8; u++) *(bf16x8*)&Ws[wn + u * 16][wk] = wp[u];
        BAR_LIGHT();   // staging visible
        if (c < 7) {
            const int kc0 = (c + 1) * 128;
            yp = *(const bf16x8*)&Y[(size_t)(row0 + yr) * 1024 + kc0 + yk];
            #pragma unroll
            for (int u = 0; u < 8; u++)
                wp[u] = *(const bf16x8*)&woT[(size_t)(wn + u * 16) * 1024 + kc0 + wk];
        }
        #pragma unroll
        for (int kc = 0; kc < 4; kc++) {
            bf16x8 a = *(const bf16x8*)&Ys[m16][kc * 32 + g4 * 8];
            #pragma unroll
            for (int nt = 0; nt < 2; nt++) {
                bf16x8 bb = *(const bf16x8*)&Ws[n0 + nt * 16 + m16][kc * 32 + g4 * 8];
                acc[nt] = __builtin_amdgcn_mfma_f32_16x16x32_bf16(a, bb, acc[nt], 0, 0, 0);
            }
        }
    }
    BAR_LIGHT();   // done reading Ws; reuse as fp32 epilogue staging

    float* Ot = (float*)&Ws[0][0];  // stride 132, 16x132 floats fits in Ws
    #pragma unroll
    for (int nt = 0; nt < 2; nt++)
        #pragma unroll
        for (int r = 0; r < 4; r++) {
            int rowl = g4 * 4 + r;
            int col = n0 + nt * 16 + m16;
            Ot[rowl * 132 + col] = (acc[nt][r] + boS[col]) * mskS[rowl];
        }
    BAR_LIGHT();
    #pragma unroll
    for (int u = 0; u < 2; u++) {
        int lin = t + 256 * u; int r = lin >> 5, c4 = lin & 31;
        *(float4*)&out[(size_t)(row0 + r) * 128 + c4 * 4] =
            *(const float4*)&Ot[r * 132 + c4 * 4];
    }
}

extern "C" void kernel_launch(void* const* d_in, const int* in_sizes, int n_in,
                              void* d_out, int out_size, void* d_ws, size_t ws_size,
                              hipStream_t stream) {
    const float* x    = (const float*)d_in[0];
    const float* dist = (const float*)d_in[1];
    const float* mask = (const float*)d_in[2];
    const float* Wq   = (const float*)d_in[3];
    const float* bq   = (const float*)d_in[4];
    const float* Wk   = (const float*)d_in[5];
    const float* bk   = (const float*)d_in[6];
    const float* Wv   = (const float*)d_in[7];
    const float* bv   = (const float*)d_in[8];
    const float* Wo   = (const float*)d_in[9];
    const float* bo   = (const float*)d_in[10];
    float* out = (float*)d_out;

    const size_t perE = (size_t)B_ * H_ * N_ * D_;     // 8,388,608 elements
    unsigned short* qb  = (unsigned short*)d_ws;       // bf16 (B,H,N,D)
    unsigned short* kb  = qb + perE;                   // bf16 (B,H,N,D)
    unsigned short* vb  = kb + perE;                   // f16  (B,H,D,N)
    unsigned short* yb  = vb + perE;                   // bf16 (B,N,H*D)
    unsigned short* wTh = yb + perE;                   // [3][1024][128]
    unsigned short* woT = wTh + 3 * 131072;            // [128][1024]
    // xh ALIASES yb: xh written by prep, read by qkv; yb first written by
    // attn (after qkv). Lifetimes disjoint; footprint = R17 layout exactly.
    unsigned short* xh  = yb;                          // bf16 x (B,N,D) 1M elems

    prep_kernel<<<1024, 256, 0, stream>>>(Wq, Wk, Wv, Wo, x, wTh, woT, xh);
    qkv_kernel<<<1536, 256, 0, stream>>>(xh, mask, wTh, bq, bk, bv, qb, kb, vb);
    attn_kernel<<<512, 256, 0, stream>>>(qb, kb, vb, dist, mask, yb);
    oproj_kernel<<<256 * 2, 256, 0, stream>>>(yb, woT, bo, mask, out);
}